// Round 4
// baseline (469.561 us; speedup 1.0000x reference)
//
#include <hip/hip_runtime.h>

// IVP loss: Euler-integrate trajectories through vf_pred and vf_true
// (bilinear sampling, coords clipped), MSE over (n_steps+1,B,2,H,W).
//
// R3:
//  - interleaved (H,W) float2 fields (prepass) + row-pair dwordx4 gathers:
//    corners (y,x0),(y,x0+1) fetched by ONE 16B load. x clamped to the
//    largest float < W-1 so ix1=ix0+1 is always in-bounds (error ~6e-5*|df|,
//    threshold 3.5e-2).
//  - step 0 specialization: integer positions => bilinear == direct coalesced
//    load, shared by both trajectories.
//  - no memset / finalize launches: prepass zeroes acc+counter, last main
//    block writes the output (atomic counter + device-scope atomics).

constexpr int   Bn      = 8;
constexpr int   Hn      = 768;
constexpr int   Wn      = 768;
constexpr int   HWn     = Hn * Wn;
constexpr int   NSTEPS  = 8;
constexpr float DXC     = 0.5f;
constexpr int   TPB     = 256;
constexpr int   PPT     = 2;                              // chains per thread
constexpr int   PIX_PER_BLOCK    = TPB * PPT;             // 512
constexpr int   BLOCKS_PER_BATCH = HWn / PIX_PER_BLOCK;   // 1152
constexpr int   MAIN_BLOCKS      = Bn * BLOCKS_PER_BATCH; // 9216
constexpr double TOTAL_ELEMS = (double)(NSTEPS + 1) * Bn * 2 * HWn;
// largest float strictly below 767.0 (spacing at 2^9 is 2^-14)
constexpr float XMAX = 766.99993896484375f;

typedef float f4v __attribute__((ext_vector_type(4), aligned(8)));

// ---------------- prepass: planar -> interleaved float2, zero acc ----------
__global__ __launch_bounds__(256)
void interleave_kernel(const float* __restrict__ vp,
                       const float* __restrict__ vt,
                       float2* __restrict__ wp,
                       float2* __restrict__ wt,
                       double* __restrict__ acc,
                       int* __restrict__ counter) {
    int t = blockIdx.x * blockDim.x + threadIdx.x;
    if (t == 0) { acc[0] = 0.0; counter[0] = 0; }
    int base = t * 4;                    // HWn % 4 == 0
    int b    = base / HWn;
    int p    = base - b * HWn;
    {
        const float* px = vp + (size_t)b * 2 * HWn + p;
        float4 xs = *(const float4*)px;
        float4 ys = *(const float4*)(px + HWn);
        float4* o = (float4*)(wp + (size_t)b * HWn + p);
        o[0] = {xs.x, ys.x, xs.y, ys.y};
        o[1] = {xs.z, ys.z, xs.w, ys.w};
    }
    {
        const float* px = vt + (size_t)b * 2 * HWn + p;
        float4 xs = *(const float4*)px;
        float4 ys = *(const float4*)(px + HWn);
        float4* o = (float4*)(wt + (size_t)b * HWn + p);
        o[0] = {xs.x, ys.x, xs.y, ys.y};
        o[1] = {xs.z, ys.z, xs.w, ys.w};
    }
}

// ---------------- helpers ----------------
__device__ __forceinline__ void gaddr(float x, float y,
                                      int& o0, int& o1,
                                      float& wx, float& wy) {
    x = fminf(fmaxf(x, 0.0f), XMAX);
    y = fminf(fmaxf(y, 0.0f), (float)(Hn - 1));
    float x0f = floorf(x), y0f = floorf(y);
    wx = x - x0f; wy = y - y0f;
    int ix0 = (int)x0f, iy0 = (int)y0f;
    int iy1 = min(iy0 + 1, Hn - 1);
    o0 = iy0 * Wn + ix0;                 // ix1 = ix0+1 always valid (x<=XMAX)
    o1 = iy1 * Wn + ix0;
}

__device__ __forceinline__ f4v ld4(const float2* __restrict__ base, int idx) {
    return *(const f4v*)((const char*)base + ((long)idx << 3));
}

__device__ __forceinline__ void comb(f4v r0, f4v r1, float wx, float wy,
                                     float& ux, float& uy) {
    float wx1 = 1.0f - wx, wy1 = 1.0f - wy;
    float t0x = wx1 * r0.x + wx * r0.z;
    float t0y = wx1 * r0.y + wx * r0.w;
    float t1x = wx1 * r1.x + wx * r1.z;
    float t1y = wx1 * r1.y + wx * r1.w;
    ux = wy1 * t0x + wy * t1x;
    uy = wy1 * t0y + wy * t1y;
}

// ---------------- main: interleaved row-pair path ----------------
__global__ __launch_bounds__(TPB)
void ivp_loss_i2(const float2* __restrict__ wp,
                 const float2* __restrict__ wt,
                 double* __restrict__ acc,
                 int* __restrict__ counter,
                 float* __restrict__ out) {
    int batch = blockIdx.x & 7;            // batch <-> XCD alignment
    int seq   = blockIdx.x >> 3;
    const float2* fp = wp + (size_t)batch * HWn;
    const float2* ft = wt + (size_t)batch * HWn;

    int base = seq * PIX_PER_BLOCK + (int)threadIdx.x;

    float pxp[PPT], pyp[PPT], pxt[PPT], pyt[PPT];
    float local = 0.0f;

    // step 0: integer positions -> bilinear == direct coalesced load
#pragma unroll
    for (int c = 0; c < PPT; ++c) {
        int p  = base + c * TPB;
        int yi = p / Wn;
        int xi = p - yi * Wn;
        float2 up = fp[p];
        float2 ut = ft[p];
        pxp[c] = fmaf(DXC, up.x, (float)xi);
        pyp[c] = fmaf(DXC, up.y, (float)yi);
        pxt[c] = fmaf(DXC, ut.x, (float)xi);
        pyt[c] = fmaf(DXC, ut.y, (float)yi);
        float ddx = pxt[c] - pxp[c], ddy = pyt[c] - pyp[c];
        local = fmaf(ddx, ddx, local);
        local = fmaf(ddy, ddy, local);
    }

    // steps 1..7: two-phase (issue all 8 dwordx4 gathers, then combine)
#pragma unroll
    for (int s = 1; s < NSTEPS; ++s) {
        f4v  P0[PPT], P1[PPT], T0[PPT], T1[PPT];
        float wxp[PPT], wyp[PPT], wxt[PPT], wyt[PPT];
#pragma unroll
        for (int c = 0; c < PPT; ++c) {
            int a0, a1;
            gaddr(pxp[c], pyp[c], a0, a1, wxp[c], wyp[c]);
            P0[c] = ld4(fp, a0); P1[c] = ld4(fp, a1);
            gaddr(pxt[c], pyt[c], a0, a1, wxt[c], wyt[c]);
            T0[c] = ld4(ft, a0); T1[c] = ld4(ft, a1);
        }
#pragma unroll
        for (int c = 0; c < PPT; ++c) {
            float ux, uy;
            comb(P0[c], P1[c], wxp[c], wyp[c], ux, uy);
            pxp[c] = fmaf(DXC, ux, pxp[c]);
            pyp[c] = fmaf(DXC, uy, pyp[c]);
            comb(T0[c], T1[c], wxt[c], wyt[c], ux, uy);
            pxt[c] = fmaf(DXC, ux, pxt[c]);
            pyt[c] = fmaf(DXC, uy, pyt[c]);
            float ddx = pxt[c] - pxp[c], ddy = pyt[c] - pyp[c];
            local = fmaf(ddx, ddx, local);
            local = fmaf(ddy, ddy, local);
        }
    }

    // wave64 butterfly reduce
#pragma unroll
    for (int o = 32; o > 0; o >>= 1) local += __shfl_down(local, o, 64);
    __shared__ float wsum[TPB / 64];
    int lane = threadIdx.x & 63, wid = threadIdx.x >> 6;
    if (lane == 0) wsum[wid] = local;
    __syncthreads();
    if (threadIdx.x == 0) {
        float bs = (wsum[0] + wsum[1]) + (wsum[2] + wsum[3]);
        atomicAdd(acc, (double)bs);
        __threadfence();
        int done = atomicAdd(counter, 1);
        if (done == MAIN_BLOCKS - 1) {
            double total = atomicAdd(acc, 0.0);   // device-scope read of final sum
            out[0] = (float)(total / TOTAL_ELEMS);
        }
    }
}

// ---------------- fallback: planar path (no workspace needed) --------------
__device__ __forceinline__ void bilin_planar(const float* __restrict__ vfx,
                                             const float* __restrict__ vfy,
                                             float x, float y,
                                             float& ox, float& oy) {
    x = fminf(fmaxf(x, 0.0f), (float)(Wn - 1));
    y = fminf(fmaxf(y, 0.0f), (float)(Hn - 1));
    float x0f = floorf(x), y0f = floorf(y);
    float wx = x - x0f, wy = y - y0f;
    int ix0 = (int)x0f, iy0 = (int)y0f;
    int ix1 = min(ix0 + 1, Wn - 1);
    int iy1 = min(iy0 + 1, Hn - 1);
    int i00 = iy0 * Wn + ix0, i01 = iy0 * Wn + ix1;
    int i10 = iy1 * Wn + ix0, i11 = iy1 * Wn + ix1;
    float wx1 = 1.0f - wx, wy1 = 1.0f - wy;
    ox = wy1 * (wx1 * vfx[i00] + wx * vfx[i01]) + wy * (wx1 * vfx[i10] + wx * vfx[i11]);
    oy = wy1 * (wx1 * vfy[i00] + wx * vfy[i01]) + wy * (wx1 * vfy[i10] + wx * vfy[i11]);
}

__global__ __launch_bounds__(TPB)
void ivp_loss_planar(const float* __restrict__ vp,
                     const float* __restrict__ vt,
                     double* __restrict__ acc,
                     int* __restrict__ counter,
                     float* __restrict__ out) {
    int batch = blockIdx.x & 7;
    int seq   = blockIdx.x >> 3;
    const float* vpx = vp + (size_t)batch * 2 * HWn;
    const float* vpy = vpx + HWn;
    const float* vtx = vt + (size_t)batch * 2 * HWn;
    const float* vty = vtx + HWn;
    int base = seq * PIX_PER_BLOCK + (int)threadIdx.x;
    float pxp[PPT], pyp[PPT], pxt[PPT], pyt[PPT];
#pragma unroll
    for (int c = 0; c < PPT; ++c) {
        int p  = base + c * TPB;
        int yi = p / Wn;
        int xi = p - yi * Wn;
        pxp[c] = (float)xi; pyp[c] = (float)yi;
        pxt[c] = (float)xi; pyt[c] = (float)yi;
    }
    float local = 0.0f;
#pragma unroll
    for (int s = 0; s < NSTEPS; ++s) {
#pragma unroll
        for (int c = 0; c < PPT; ++c) {
            float ux, uy;
            bilin_planar(vpx, vpy, pxp[c], pyp[c], ux, uy);
            pxp[c] = fmaf(DXC, ux, pxp[c]);
            pyp[c] = fmaf(DXC, uy, pyp[c]);
            bilin_planar(vtx, vty, pxt[c], pyt[c], ux, uy);
            pxt[c] = fmaf(DXC, ux, pxt[c]);
            pyt[c] = fmaf(DXC, uy, pyt[c]);
            float ddx = pxt[c] - pxp[c], ddy = pyt[c] - pyp[c];
            local = fmaf(ddx, ddx, local);
            local = fmaf(ddy, ddy, local);
        }
    }
#pragma unroll
    for (int o = 32; o > 0; o >>= 1) local += __shfl_down(local, o, 64);
    __shared__ float wsum[TPB / 64];
    int lane = threadIdx.x & 63, wid = threadIdx.x >> 6;
    if (lane == 0) wsum[wid] = local;
    __syncthreads();
    if (threadIdx.x == 0) {
        float bs = (wsum[0] + wsum[1]) + (wsum[2] + wsum[3]);
        atomicAdd(acc, (double)bs);
        __threadfence();
        int done = atomicAdd(counter, 1);
        if (done == MAIN_BLOCKS - 1) {
            double total = atomicAdd(acc, 0.0);
            out[0] = (float)(total / TOTAL_ELEMS);
        }
    }
}

__global__ void zero_acc_kernel(double* __restrict__ acc, int* __restrict__ counter) {
    acc[0] = 0.0; counter[0] = 0;
}

extern "C" void kernel_launch(void* const* d_in, const int* in_sizes, int n_in,
                              void* d_out, int out_size, void* d_ws, size_t ws_size,
                              hipStream_t stream) {
    const float* vp = (const float*)d_in[0];  // vf_pred
    const float* vt = (const float*)d_in[1];  // vf_true
    double* acc     = (double*)d_ws;
    int*    counter = (int*)((char*)d_ws + 8);
    float*  out     = (float*)d_out;

    const size_t field_bytes = (size_t)Bn * HWn * sizeof(float2);   // 37.75 MB
    const size_t need = 256 + 2 * field_bytes;

    if (ws_size >= need) {
        float2* wpi = (float2*)((char*)d_ws + 256);
        float2* wti = (float2*)((char*)d_ws + 256 + field_bytes);
        int ithreads = Bn * HWn / 4;
        interleave_kernel<<<ithreads / 256, 256, 0, stream>>>(vp, vt, wpi, wti, acc, counter);
        ivp_loss_i2<<<MAIN_BLOCKS, TPB, 0, stream>>>(wpi, wti, acc, counter, out);
    } else {
        zero_acc_kernel<<<1, 1, 0, stream>>>(acc, counter);
        ivp_loss_planar<<<MAIN_BLOCKS, TPB, 0, stream>>>(vp, vt, acc, counter, out);
    }
}

// Round 5
// 232.559 us; speedup vs baseline: 2.0191x; 2.0191x over previous
//
#include <hip/hip_runtime.h>

// IVP loss: Euler-integrate trajectories through vf_pred and vf_true
// (bilinear sampling, coords clipped), MSE over (n_steps+1,B,2,H,W).
//
// R4:
//  - REVERT R3's counter+__threadfence block tail (suspected buffer_wbl2
//    L2-maintenance per block => latency collapse). Back to finalize kernel.
//  - KEEP: interleaved float2 layout, row-pair dwordx4 gathers (XMAX clamp),
//    step-0 specialization, batch<->XCD mapping.
//  - NEW: __builtin_amdgcn_sched_barrier(0) between the per-step load
//    cluster and the combine phase — forbids the scheduler from sinking
//    gathers to their uses (R3: VGPR=32 => loads serialized; we want all 8
//    in flight before the first vmcnt wait).

constexpr int   Bn      = 8;
constexpr int   Hn      = 768;
constexpr int   Wn      = 768;
constexpr int   HWn     = Hn * Wn;
constexpr int   NSTEPS  = 8;
constexpr float DXC     = 0.5f;
constexpr int   TPB     = 256;
constexpr int   PPT     = 2;                              // chains per thread
constexpr int   PIX_PER_BLOCK    = TPB * PPT;             // 512
constexpr int   BLOCKS_PER_BATCH = HWn / PIX_PER_BLOCK;   // 1152
constexpr int   MAIN_BLOCKS      = Bn * BLOCKS_PER_BATCH; // 9216
constexpr double TOTAL_ELEMS = (double)(NSTEPS + 1) * Bn * 2 * HWn;
// largest float strictly below 767.0: keeps ix1=ix0+1 in-bounds, error ~6e-5
constexpr float XMAX = 766.99993896484375f;

typedef float f4v __attribute__((ext_vector_type(4), aligned(8)));

// ---------------- prepass: planar -> interleaved float2, zero acc ----------
__global__ __launch_bounds__(256)
void interleave_kernel(const float* __restrict__ vp,
                       const float* __restrict__ vt,
                       float2* __restrict__ wp,
                       float2* __restrict__ wt,
                       double* __restrict__ acc) {
    int t = blockIdx.x * blockDim.x + threadIdx.x;
    if (t == 0) acc[0] = 0.0;
    int base = t * 4;                    // HWn % 4 == 0
    int b    = base / HWn;
    int p    = base - b * HWn;
    {
        const float* px = vp + (size_t)b * 2 * HWn + p;
        float4 xs = *(const float4*)px;
        float4 ys = *(const float4*)(px + HWn);
        float4* o = (float4*)(wp + (size_t)b * HWn + p);
        o[0] = {xs.x, ys.x, xs.y, ys.y};
        o[1] = {xs.z, ys.z, xs.w, ys.w};
    }
    {
        const float* px = vt + (size_t)b * 2 * HWn + p;
        float4 xs = *(const float4*)px;
        float4 ys = *(const float4*)(px + HWn);
        float4* o = (float4*)(wt + (size_t)b * HWn + p);
        o[0] = {xs.x, ys.x, xs.y, ys.y};
        o[1] = {xs.z, ys.z, xs.w, ys.w};
    }
}

// ---------------- helpers ----------------
__device__ __forceinline__ void gaddr(float x, float y,
                                      int& o0, int& o1,
                                      float& wx, float& wy) {
    x = fminf(fmaxf(x, 0.0f), XMAX);
    y = fminf(fmaxf(y, 0.0f), (float)(Hn - 1));
    float x0f = floorf(x), y0f = floorf(y);
    wx = x - x0f; wy = y - y0f;
    int ix0 = (int)x0f, iy0 = (int)y0f;
    int iy1 = min(iy0 + 1, Hn - 1);
    o0 = iy0 * Wn + ix0;                 // ix1 = ix0+1 always valid (x<=XMAX)
    o1 = iy1 * Wn + ix0;
}

__device__ __forceinline__ f4v ld4(const float2* __restrict__ base, int idx) {
    return *(const f4v*)((const char*)base + ((long)idx << 3));
}

__device__ __forceinline__ void comb(f4v r0, f4v r1, float wx, float wy,
                                     float& ux, float& uy) {
    float wx1 = 1.0f - wx, wy1 = 1.0f - wy;
    float t0x = wx1 * r0.x + wx * r0.z;
    float t0y = wx1 * r0.y + wx * r0.w;
    float t1x = wx1 * r1.x + wx * r1.z;
    float t1y = wx1 * r1.y + wx * r1.w;
    ux = wy1 * t0x + wy * t1x;
    uy = wy1 * t0y + wy * t1y;
}

// ---------------- main: interleaved row-pair path ----------------
__global__ __launch_bounds__(TPB)
void ivp_loss_i2(const float2* __restrict__ wp,
                 const float2* __restrict__ wt,
                 double* __restrict__ acc) {
    int batch = blockIdx.x & 7;            // batch <-> XCD alignment
    int seq   = blockIdx.x >> 3;
    const float2* fp = wp + (size_t)batch * HWn;
    const float2* ft = wt + (size_t)batch * HWn;

    int base = seq * PIX_PER_BLOCK + (int)threadIdx.x;

    float pxp[PPT], pyp[PPT], pxt[PPT], pyt[PPT];
    float local = 0.0f;

    // step 0: integer positions -> bilinear == direct coalesced load
#pragma unroll
    for (int c = 0; c < PPT; ++c) {
        int p  = base + c * TPB;
        int yi = p / Wn;
        int xi = p - yi * Wn;
        float2 up = fp[p];
        float2 ut = ft[p];
        pxp[c] = fmaf(DXC, up.x, (float)xi);
        pyp[c] = fmaf(DXC, up.y, (float)yi);
        pxt[c] = fmaf(DXC, ut.x, (float)xi);
        pyt[c] = fmaf(DXC, ut.y, (float)yi);
        float ddx = pxt[c] - pxp[c], ddy = pyt[c] - pyp[c];
        local = fmaf(ddx, ddx, local);
        local = fmaf(ddy, ddy, local);
    }

    // steps 1..7: load-cluster phase, sched_barrier, combine phase
#pragma unroll
    for (int s = 1; s < NSTEPS; ++s) {
        f4v  P0[PPT], P1[PPT], T0[PPT], T1[PPT];
        float wxp[PPT], wyp[PPT], wxt[PPT], wyt[PPT];
#pragma unroll
        for (int c = 0; c < PPT; ++c) {
            int a0, a1;
            gaddr(pxp[c], pyp[c], a0, a1, wxp[c], wyp[c]);
            P0[c] = ld4(fp, a0); P1[c] = ld4(fp, a1);
            gaddr(pxt[c], pyt[c], a0, a1, wxt[c], wyt[c]);
            T0[c] = ld4(ft, a0); T1[c] = ld4(ft, a1);
        }
        // pin: all 8 gathers issued before any combine VALU sinks above them
        __builtin_amdgcn_sched_barrier(0);
#pragma unroll
        for (int c = 0; c < PPT; ++c) {
            float ux, uy;
            comb(P0[c], P1[c], wxp[c], wyp[c], ux, uy);
            pxp[c] = fmaf(DXC, ux, pxp[c]);
            pyp[c] = fmaf(DXC, uy, pyp[c]);
            comb(T0[c], T1[c], wxt[c], wyt[c], ux, uy);
            pxt[c] = fmaf(DXC, ux, pxt[c]);
            pyt[c] = fmaf(DXC, uy, pyt[c]);
            float ddx = pxt[c] - pxp[c], ddy = pyt[c] - pyp[c];
            local = fmaf(ddx, ddx, local);
            local = fmaf(ddy, ddy, local);
        }
    }

    // wave64 butterfly reduce
#pragma unroll
    for (int o = 32; o > 0; o >>= 1) local += __shfl_down(local, o, 64);
    __shared__ float wsum[TPB / 64];
    int lane = threadIdx.x & 63, wid = threadIdx.x >> 6;
    if (lane == 0) wsum[wid] = local;
    __syncthreads();
    if (threadIdx.x == 0) {
        float bs = (wsum[0] + wsum[1]) + (wsum[2] + wsum[3]);
        atomicAdd(acc, (double)bs);
    }
}

// ---------------- fallback: planar path (no workspace needed) --------------
__device__ __forceinline__ void bilin_planar(const float* __restrict__ vfx,
                                             const float* __restrict__ vfy,
                                             float x, float y,
                                             float& ox, float& oy) {
    x = fminf(fmaxf(x, 0.0f), (float)(Wn - 1));
    y = fminf(fmaxf(y, 0.0f), (float)(Hn - 1));
    float x0f = floorf(x), y0f = floorf(y);
    float wx = x - x0f, wy = y - y0f;
    int ix0 = (int)x0f, iy0 = (int)y0f;
    int ix1 = min(ix0 + 1, Wn - 1);
    int iy1 = min(iy0 + 1, Hn - 1);
    int i00 = iy0 * Wn + ix0, i01 = iy0 * Wn + ix1;
    int i10 = iy1 * Wn + ix0, i11 = iy1 * Wn + ix1;
    float wx1 = 1.0f - wx, wy1 = 1.0f - wy;
    ox = wy1 * (wx1 * vfx[i00] + wx * vfx[i01]) + wy * (wx1 * vfx[i10] + wx * vfx[i11]);
    oy = wy1 * (wx1 * vfy[i00] + wx * vfy[i01]) + wy * (wx1 * vfy[i10] + wx * vfy[i11]);
}

__global__ __launch_bounds__(TPB)
void ivp_loss_planar(const float* __restrict__ vp,
                     const float* __restrict__ vt,
                     double* __restrict__ acc) {
    int batch = blockIdx.x & 7;
    int seq   = blockIdx.x >> 3;
    const float* vpx = vp + (size_t)batch * 2 * HWn;
    const float* vpy = vpx + HWn;
    const float* vtx = vt + (size_t)batch * 2 * HWn;
    const float* vty = vtx + HWn;
    int base = seq * PIX_PER_BLOCK + (int)threadIdx.x;
    float pxp[PPT], pyp[PPT], pxt[PPT], pyt[PPT];
#pragma unroll
    for (int c = 0; c < PPT; ++c) {
        int p  = base + c * TPB;
        int yi = p / Wn;
        int xi = p - yi * Wn;
        pxp[c] = (float)xi; pyp[c] = (float)yi;
        pxt[c] = (float)xi; pyt[c] = (float)yi;
    }
    float local = 0.0f;
#pragma unroll
    for (int s = 0; s < NSTEPS; ++s) {
#pragma unroll
        for (int c = 0; c < PPT; ++c) {
            float ux, uy;
            bilin_planar(vpx, vpy, pxp[c], pyp[c], ux, uy);
            pxp[c] = fmaf(DXC, ux, pxp[c]);
            pyp[c] = fmaf(DXC, uy, pyp[c]);
            bilin_planar(vtx, vty, pxt[c], pyt[c], ux, uy);
            pxt[c] = fmaf(DXC, ux, pxt[c]);
            pyt[c] = fmaf(DXC, uy, pyt[c]);
            float ddx = pxt[c] - pxp[c], ddy = pyt[c] - pyp[c];
            local = fmaf(ddx, ddx, local);
            local = fmaf(ddy, ddy, local);
        }
    }
#pragma unroll
    for (int o = 32; o > 0; o >>= 1) local += __shfl_down(local, o, 64);
    __shared__ float wsum[TPB / 64];
    int lane = threadIdx.x & 63, wid = threadIdx.x >> 6;
    if (lane == 0) wsum[wid] = local;
    __syncthreads();
    if (threadIdx.x == 0) {
        float bs = (wsum[0] + wsum[1]) + (wsum[2] + wsum[3]);
        atomicAdd(acc, (double)bs);
    }
}

__global__ void zero_acc_kernel(double* __restrict__ acc) { acc[0] = 0.0; }

__global__ void finalize_kernel(const double* __restrict__ acc,
                                float* __restrict__ out) {
    out[0] = (float)(acc[0] / TOTAL_ELEMS);
}

extern "C" void kernel_launch(void* const* d_in, const int* in_sizes, int n_in,
                              void* d_out, int out_size, void* d_ws, size_t ws_size,
                              hipStream_t stream) {
    const float* vp = (const float*)d_in[0];  // vf_pred
    const float* vt = (const float*)d_in[1];  // vf_true
    double* acc = (double*)d_ws;
    float*  out = (float*)d_out;

    const size_t field_bytes = (size_t)Bn * HWn * sizeof(float2);   // 37.75 MB
    const size_t need = 256 + 2 * field_bytes;

    if (ws_size >= need) {
        float2* wpi = (float2*)((char*)d_ws + 256);
        float2* wti = (float2*)((char*)d_ws + 256 + field_bytes);
        int ithreads = Bn * HWn / 4;
        interleave_kernel<<<ithreads / 256, 256, 0, stream>>>(vp, vt, wpi, wti, acc);
        ivp_loss_i2<<<MAIN_BLOCKS, TPB, 0, stream>>>(wpi, wti, acc);
    } else {
        zero_acc_kernel<<<1, 1, 0, stream>>>(acc);
        ivp_loss_planar<<<MAIN_BLOCKS, TPB, 0, stream>>>(vp, vt, acc);
    }
    finalize_kernel<<<1, 1, 0, stream>>>(acc, out);
}